// Round 1
// baseline (494.398 us; speedup 1.0000x reference)
//
#include <hip/hip_runtime.h>
#include <stdint.h>

#define M_DIM 8192
#define N_DIM 8192
#define K_DIM 64

typedef __attribute__((ext_vector_type(8))) short short8;   // 8 bf16 = 4 VGPRs
typedef __attribute__((ext_vector_type(4))) float f32x4;

__device__ __forceinline__ ushort f2bf(float f) {
    // round-to-nearest-even fp32 -> bf16 (inputs are finite, no NaN handling needed)
    uint u = __float_as_uint(f);
    uint r = (u + 0x7FFFu + ((u >> 16) & 1u)) >> 16;
    return (ushort)r;
}

// y [M,64] fp32 -> yb [M,64] bf16, straight copy/convert. 4 elems/thread.
__global__ __launch_bounds__(256) void prep_y(const float* __restrict__ y,
                                              ushort* __restrict__ yb) {
    int i = (blockIdx.x * 256 + threadIdx.x) * 4;
    float4 v = *(const float4*)(y + i);
    ushort4 o;
    o.x = f2bf(v.x); o.y = f2bf(v.y); o.z = f2bf(v.z); o.w = f2bf(v.w);
    *(ushort4*)(yb + i) = o;
}

// z [64,N] fp32 -> zt [N,64] bf16 (transpose). One thread per column n.
// Reads are coalesced (lane n reads z[k][n]); each thread writes its own
// contiguous 128B row of zt. Total 1 MB written — negligible.
__global__ __launch_bounds__(256) void prep_zt(const float* __restrict__ z,
                                               ushort* __restrict__ zt) {
    int n = blockIdx.x * 256 + threadIdx.x;
    uint w[32];
#pragma unroll
    for (int k = 0; k < 64; k += 2) {
        ushort a = f2bf(z[(size_t)k * N_DIM + n]);
        ushort b = f2bf(z[(size_t)(k + 1) * N_DIM + n]);
        w[k >> 1] = (uint)a | ((uint)b << 16);
    }
    uint4* dst = (uint4*)(zt + (size_t)n * 64);
#pragma unroll
    for (int j = 0; j < 8; ++j)
        dst[j] = make_uint4(w[4 * j], w[4 * j + 1], w[4 * j + 2], w[4 * j + 3]);
}

// Main: block = 256 threads = 4 waves; block tile 64x64; wave tile 32x32.
// No LDS: A/B fragments loaded directly from L2-resident yb/zt as dwordx4.
// A layout (16x16x32 bf16): lane l holds A[m=l&15][k=(l>>4)*8+j]  (m120-verified)
// B layout: mirror,         lane l holds B[k=(l>>4)*8+j][n=l&15]
// C layout: col=l&15, row=(l>>4)*4+reg                            (m89-verified)
__global__ __launch_bounds__(256) void sddmm_main(const float* __restrict__ x,
                                                  const ushort* __restrict__ yb,
                                                  const ushort* __restrict__ zt,
                                                  float* __restrict__ out) {
    const int tid  = threadIdx.x;
    const int wave = tid >> 6;
    const int l    = tid & 63;
    const int q    = l >> 4;    // 0..3
    const int r16  = l & 15;    // 0..15
    const int m0 = blockIdx.y * 64 + (wave >> 1) * 32;
    const int n0 = blockIdx.x * 64 + (wave & 1) * 32;

    short8 a[2][2], b[2][2];
#pragma unroll
    for (int mi = 0; mi < 2; ++mi)
#pragma unroll
        for (int kc = 0; kc < 2; ++kc) {
            int row = m0 + 16 * mi + r16;
            int k   = 32 * kc + 8 * q;
            a[mi][kc] = *(const short8*)(yb + (size_t)row * 64 + k);
        }
#pragma unroll
    for (int ni = 0; ni < 2; ++ni)
#pragma unroll
        for (int kc = 0; kc < 2; ++kc) {
            int col = n0 + 16 * ni + r16;
            int k   = 32 * kc + 8 * q;
            b[ni][kc] = *(const short8*)(zt + (size_t)col * 64 + k);
        }

    f32x4 acc[2][2] = {};
#pragma unroll
    for (int kc = 0; kc < 2; ++kc)
#pragma unroll
        for (int mi = 0; mi < 2; ++mi)
#pragma unroll
            for (int ni = 0; ni < 2; ++ni)
                acc[mi][ni] = __builtin_amdgcn_mfma_f32_16x16x32_bf16(
                    a[mi][kc], b[ni][kc], acc[mi][ni], 0, 0, 0);

    // Epilogue: out = x * acc. Each store instr covers 4 aligned 64B segments.
#pragma unroll
    for (int mi = 0; mi < 2; ++mi)
#pragma unroll
        for (int r = 0; r < 4; ++r)
#pragma unroll
            for (int ni = 0; ni < 2; ++ni) {
                int col  = n0 + 16 * ni + r16;
                int row  = m0 + 16 * mi + q * 4 + r;
                size_t idx = (size_t)row * N_DIM + col;
                out[idx] = x[idx] * acc[mi][ni][r];
            }
}

// Fallback if ws_size is too small for the 2MB bf16 staging (correct but slow).
__global__ __launch_bounds__(256) void sddmm_naive(const float* __restrict__ x,
                                                   const float* __restrict__ y,
                                                   const float* __restrict__ z,
                                                   float* __restrict__ out) {
    size_t i = (size_t)blockIdx.x * 256 + threadIdx.x;
    size_t total = (size_t)M_DIM * N_DIM;
    for (; i < total; i += (size_t)gridDim.x * 256) {
        int m = (int)(i / N_DIM);
        int n = (int)(i % N_DIM);
        float acc = 0.f;
        for (int k = 0; k < K_DIM; ++k)
            acc += y[(size_t)m * K_DIM + k] * z[(size_t)k * N_DIM + n];
        out[i] = x[i] * acc;
    }
}

extern "C" void kernel_launch(void* const* d_in, const int* in_sizes, int n_in,
                              void* d_out, int out_size, void* d_ws, size_t ws_size,
                              hipStream_t stream) {
    const float* x = (const float*)d_in[0];
    const float* y = (const float*)d_in[1];
    const float* z = (const float*)d_in[2];
    float* out = (float*)d_out;

    size_t need = (size_t)M_DIM * K_DIM * sizeof(ushort)   // yb: 1 MB
                + (size_t)N_DIM * K_DIM * sizeof(ushort);  // zt: 1 MB
    if (ws_size < need) {
        sddmm_naive<<<32768, 256, 0, stream>>>(x, y, z, out);
        return;
    }

    ushort* yb = (ushort*)d_ws;
    ushort* zt = yb + (size_t)M_DIM * K_DIM;

    prep_y<<<(M_DIM * K_DIM) / (256 * 4), 256, 0, stream>>>(y, yb);
    prep_zt<<<N_DIM / 256, 256, 0, stream>>>(z, zt);

    dim3 grid(N_DIM / 64, M_DIM / 64);
    sddmm_main<<<grid, 256, 0, stream>>>(x, yb, zt, out);
}

// Round 2
// 426.322 us; speedup vs baseline: 1.1597x; 1.1597x over previous
//
#include <hip/hip_runtime.h>
#include <stdint.h>

#define M_DIM 8192
#define N_DIM 8192
#define K_DIM 64
#define BM 32
#define BN 256
#define LDS_STRIDE 260  // 256 + 4-float pad: keeps acc b32 writes <=2-way bank aliased (free), 16B aligned reads

typedef __attribute__((ext_vector_type(8))) short short8;   // 8 bf16 = 4 VGPRs
typedef __attribute__((ext_vector_type(4))) float f32x4;

__device__ __forceinline__ ushort f2bf(float f) {
    // round-to-nearest-even fp32 -> bf16 (inputs finite, no NaN handling needed)
    uint u = __float_as_uint(f);
    uint r = (u + 0x7FFFu + ((u >> 16) & 1u)) >> 16;
    return (ushort)r;
}

// y [M,64] fp32 -> yb [M,64] bf16. 4 elems/thread, fully coalesced.
__global__ __launch_bounds__(256) void prep_y(const float* __restrict__ y,
                                              ushort* __restrict__ yb) {
    int i = (blockIdx.x * 256 + threadIdx.x) * 4;
    float4 v = *(const float4*)(y + i);
    ushort4 o;
    o.x = f2bf(v.x); o.y = f2bf(v.y); o.z = f2bf(v.z); o.w = f2bf(v.w);
    *(ushort4*)(yb + i) = o;
}

// z [64,N] fp32 -> zt [N,64] bf16 (transpose). 4x more parallel than R1:
// block = 64 cols x 4 k-chunks of 16. Reads coalesced (256B/instr), writes
// 32B/lane into zt rows. 128 blocks. Total 2MB read / 1MB write.
__global__ __launch_bounds__(256) void prep_zt(const float* __restrict__ z,
                                               ushort* __restrict__ zt) {
    int n  = blockIdx.x * 64 + (threadIdx.x & 63);
    int k0 = (threadIdx.x >> 6) * 16;
    uint w[8];
#pragma unroll
    for (int j = 0; j < 8; ++j) {
        ushort a = f2bf(z[(size_t)(k0 + 2 * j) * N_DIM + n]);
        ushort b = f2bf(z[(size_t)(k0 + 2 * j + 1) * N_DIM + n]);
        w[j] = (uint)a | ((uint)b << 16);
    }
    uint4* dst = (uint4*)(zt + (size_t)n * 64 + k0);
    dst[0] = make_uint4(w[0], w[1], w[2], w[3]);
    dst[1] = make_uint4(w[4], w[5], w[6], w[7]);
}

// Main: block = 256 threads = 4 waves; block tile 32(M) x 256(N).
// Wave w computes the 32x64 subtile at cols [w*64, w*64+64) via 16 MFMAs
// (16x16x32 bf16), frags loaded straight from L2-resident yb/zt (dwordx4).
// Accumulators are re-laid-out through LDS so the global epilogue moves
// 1 KB contiguous per wave-instruction (dwordx4/lane over a full block row),
// fixing R1's 128B-burst DRAM inefficiency (2.2 TB/s observed).
// Layouts (verified in R1, absmax 0.25):
//   A: lane l holds A[m=l&15][k=(l>>4)*8+j]
//   B: lane l holds B[k=(l>>4)*8+j][n=l&15]
//   C: col=l&15, row=(l>>4)*4+reg
__global__ __launch_bounds__(256) void sddmm_main(const float* __restrict__ x,
                                                  const ushort* __restrict__ yb,
                                                  const ushort* __restrict__ zt,
                                                  float* __restrict__ out) {
    __shared__ float lds[BM * LDS_STRIDE];

    const int tid = threadIdx.x;
    const int wv  = tid >> 6;
    const int l   = tid & 63;
    const int q   = l >> 4;    // 0..3
    const int r16 = l & 15;    // 0..15
    const int m0 = blockIdx.y * BM;
    const int n0 = blockIdx.x * BN;

    short8 a[2][2], b[4][2];
#pragma unroll
    for (int mi = 0; mi < 2; ++mi)
#pragma unroll
        for (int kc = 0; kc < 2; ++kc)
            a[mi][kc] = *(const short8*)(yb + (size_t)(m0 + 16 * mi + r16) * 64 + 32 * kc + 8 * q);
#pragma unroll
    for (int ni = 0; ni < 4; ++ni)
#pragma unroll
        for (int kc = 0; kc < 2; ++kc)
            b[ni][kc] = *(const short8*)(zt + (size_t)(n0 + wv * 64 + 16 * ni + r16) * 64 + 32 * kc + 8 * q);

    f32x4 acc[2][4] = {};
#pragma unroll
    for (int kc = 0; kc < 2; ++kc)
#pragma unroll
        for (int mi = 0; mi < 2; ++mi)
#pragma unroll
            for (int ni = 0; ni < 4; ++ni)
                acc[mi][ni] = __builtin_amdgcn_mfma_f32_16x16x32_bf16(
                    a[mi][kc], b[ni][kc], acc[mi][ni], 0, 0, 0);

    // Scatter accumulators into the LDS tile (row-major, padded stride).
    // Per-instr bank aliasing <=2-way (free, m136).
#pragma unroll
    for (int mi = 0; mi < 2; ++mi)
#pragma unroll
        for (int ni = 0; ni < 4; ++ni)
#pragma unroll
            for (int r = 0; r < 4; ++r)
                lds[(16 * mi + 4 * q + r) * LDS_STRIDE + wv * 64 + 16 * ni + r16] = acc[mi][ni][r];

    __syncthreads();

    // Block-wide epilogue: pass p covers rows {4p+0..4p+3}; wave wv handles
    // row 4p+wv with 64 lanes x float4 = 1 KB contiguous load+store.
    const int c  = tid & 63;
    const int rw = tid >> 6;
    const size_t base = (size_t)(m0 + rw) * N_DIM + n0 + 4 * c;

    f32x4 xv[8];
#pragma unroll
    for (int p = 0; p < 8; ++p)
        xv[p] = *(const f32x4*)(x + base + (size_t)(4 * p) * N_DIM);

#pragma unroll
    for (int p = 0; p < 8; ++p) {
        f32x4 cv = *(const f32x4*)(&lds[(4 * p + rw) * LDS_STRIDE + 4 * c]);
        f32x4 o  = cv * xv[p];
        *(f32x4*)(out + base + (size_t)(4 * p) * N_DIM) = o;
    }
}

// Fallback if ws_size is too small for the 2MB bf16 staging (correct but slow).
__global__ __launch_bounds__(256) void sddmm_naive(const float* __restrict__ x,
                                                   const float* __restrict__ y,
                                                   const float* __restrict__ z,
                                                   float* __restrict__ out) {
    size_t i = (size_t)blockIdx.x * 256 + threadIdx.x;
    size_t total = (size_t)M_DIM * N_DIM;
    for (; i < total; i += (size_t)gridDim.x * 256) {
        int m = (int)(i / N_DIM);
        int n = (int)(i % N_DIM);
        float acc = 0.f;
        for (int k = 0; k < K_DIM; ++k)
            acc += y[(size_t)m * K_DIM + k] * z[(size_t)k * N_DIM + n];
        out[i] = x[i] * acc;
    }
}

extern "C" void kernel_launch(void* const* d_in, const int* in_sizes, int n_in,
                              void* d_out, int out_size, void* d_ws, size_t ws_size,
                              hipStream_t stream) {
    const float* x = (const float*)d_in[0];
    const float* y = (const float*)d_in[1];
    const float* z = (const float*)d_in[2];
    float* out = (float*)d_out;

    size_t need = (size_t)M_DIM * K_DIM * sizeof(ushort)   // yb: 1 MB
                + (size_t)N_DIM * K_DIM * sizeof(ushort);  // zt: 1 MB
    if (ws_size < need) {
        sddmm_naive<<<32768, 256, 0, stream>>>(x, y, z, out);
        return;
    }

    ushort* yb = (ushort*)d_ws;
    ushort* zt = yb + (size_t)M_DIM * K_DIM;

    prep_y<<<(M_DIM * K_DIM) / (256 * 4), 256, 0, stream>>>(y, yb);
    prep_zt<<<N_DIM / 64, 256, 0, stream>>>(z, zt);

    dim3 grid(N_DIM / BN, M_DIM / BM);
    sddmm_main<<<grid, 256, 0, stream>>>(x, yb, zt, out);
}